// Round 7
// baseline (300.957 us; speedup 1.0000x reference)
//
#include <hip/hip_runtime.h>
#include <math.h>

typedef _Float16 h16;

#define DEV static __device__ __forceinline__

constexpr int B_ = 8, C_ = 128, L_ = 4096, OUT_ = 128;
constexpr int NCH = 4, DM = 32, DS = 16, DI = 64;
constexpr int NI = 32;            // B_*NCH instances
constexpr int NSEG = 128;         // scan segments
constexpr int SL = L_ / NSEG;     // 32 steps per segment

DEV float sigmoidf_(float x) { return 1.f / (1.f + __expf(-x)); }
DEV float siluf_(float x) { return x * sigmoidf_(x); }
DEV float softplusf_(float x) { return (x > 20.f) ? x : __logf(1.f + __expf(x)); }

template <int CTRL>
DEV float dpp_add_(float x) {
  int v = __builtin_amdgcn_update_dpp(0, __float_as_int(x), CTRL, 0xf, 0xf, false);
  return x + __int_as_float(v);
}

// ---------------- K1: LayerNorm1 (B,C,L)->(B,L,C) + token sums ----------------
__global__ __launch_bounds__(256) void k1_ln(const float* __restrict__ x,
                                             const float* __restrict__ gn,
                                             const float* __restrict__ bn,
                                             float* __restrict__ XN,
                                             float* __restrict__ SUMXN) {
  int bid = blockIdx.x;
  int b = bid >> 6, tile = bid & 63;
  int t0 = tile * 64;
  int tid = threadIdx.x;
  __shared__ float xT[128][65];
  __shared__ float gnS[128], bnS[128];
  __shared__ float red[256];
  if (tid < 128) { gnS[tid] = gn[tid]; bnS[tid] = bn[tid]; }
  for (int k = tid; k < 8192; k += 256) {
    int c = k >> 6, tt = k & 63;
    xT[c][tt] = x[((size_t)(b * C_ + c)) * L_ + t0 + tt];
  }
  __syncthreads();
  {
    int tok = tid >> 2, q = tid & 3;
    float s = 0.f, qq = 0.f;
#pragma unroll
    for (int j = 0; j < 32; ++j) {
      float v = xT[q + 4 * j][tok];
      s += v; qq += v * v;
    }
    s = dpp_add_<0xB1>(s); qq = dpp_add_<0xB1>(qq);
    s = dpp_add_<0x4E>(s); qq = dpp_add_<0x4E>(qq);
    float m = s * (1.f / 128.f);
    float var = qq * (1.f / 128.f) - m * m;
    float rs = rsqrtf(var + 1e-5f);
#pragma unroll
    for (int j = 0; j < 32; ++j) {
      int c = q + 4 * j;
      float v = xT[c][tok];
      xT[c][tok] = (v - m) * rs * gnS[c] + bnS[c];
    }
  }
  __syncthreads();
  float acc = 0.f;
  int cfix = tid & 127;
  for (int k = tid; k < 8192; k += 256) {
    int tt = k >> 7, c = k & 127;
    float v = xT[c][tt];
    XN[((size_t)(b * L_ + t0 + tt)) * C_ + c] = v;
    acc += v;
  }
  red[tid] = acc;
  __syncthreads();
  if (tid < 128) atomicAdd(&SUMXN[b * C_ + cfix], red[tid] + red[tid + 128]);
}

// ---------------- K2: in-proj + conv + silu + x-proj + dt (t-major outputs) ----
__global__ __launch_bounds__(256) void k2_prep(
    const float* __restrict__ in_W, const float* __restrict__ conv_W,
    const float* __restrict__ conv_b, const float* __restrict__ xproj_W,
    const float* __restrict__ dt_W, const float* __restrict__ dt_b,
    const float* __restrict__ XN, h16* __restrict__ SX2, h16* __restrict__ SDT2,
    float* __restrict__ BC2) {
  int bid = blockIdx.x;
  int i = bid >> 6, tile = bid & 63;
  int b = i >> 2, ch = i & 3;
  int t0 = tile * 64;
  int tid = threadIdx.x;
  int w = __builtin_amdgcn_readfirstlane(tid >> 6);
  int lane = tid & 63;

  __shared__ float uS[67][33];
  __shared__ float preS[67][65];
  __shared__ float xdS[64][35];
  __shared__ float convWS[64][4];
  __shared__ float dtWS[64][2];
  __shared__ float dtbS[64], cbS[64];

  convWS[tid >> 2][tid & 3] = conv_W[tid];
  if (tid < 128) dtWS[tid >> 1][tid & 1] = dt_W[tid];
  if (tid < 64) { dtbS[tid] = dt_b[tid]; cbS[tid] = conv_b[tid]; }
  const float* xn = XN + (size_t)b * L_ * C_ + ch * DM;
  for (int k = tid; k < 67 * 32; k += 256) {
    int r = k >> 5, c = k & 31;
    int tg = t0 - 3 + r;
    uS[r][c] = (tg >= 0) ? xn[(size_t)tg * C_ + c] : 0.f;
  }
  __syncthreads();
  float ur[32];
#pragma unroll
  for (int c = 0; c < 32; ++c) ur[c] = uS[lane][c];
  {
    int d0 = w * 16;
#pragma unroll 2
    for (int q = 0; q < 16; ++q) {
      int d = d0 + q;
      const float* wp = in_W + d * 32;   // wave-uniform -> s_load
      float a = 0.f;
#pragma unroll
      for (int c = 0; c < 32; ++c) a = fmaf(ur[c], wp[c], a);
      preS[lane][d] = a;
    }
  }
  if (w < 3) {
    int rh = 64 + w;
    const float* wp = in_W + lane * 32;
    float a = 0.f;
#pragma unroll
    for (int c = 0; c < 32; ++c) a = fmaf(uS[rh][c], wp[c], a);
    preS[rh][lane] = a;
  }
  __syncthreads();
  float convv[16];
  {
    int idx = 0;
    for (int k = tid; k < 4096; k += 256, ++idx) {
      int r = k >> 6, d = k & 63;
      float v = cbS[d];
#pragma unroll
      for (int j = 0; j < 4; ++j) v = fmaf(convWS[d][j], preS[r + j][d], v);
      convv[idx] = siluf_(v);
    }
  }
  __syncthreads();
  {
    int idx = 0;
    for (int k = tid; k < 4096; k += 256, ++idx) {
      int r = k >> 6, d = k & 63;
      preS[r][d] = convv[idx];
    }
  }
  __syncthreads();
  h16* SXp = SX2 + ((size_t)i * L_ + t0) * DI;
  for (int k = tid; k < 4096; k += 256) {
    int d = k & 63, r = k >> 6;
    SXp[(size_t)r * DI + d] = (h16)preS[r][d];
  }
  {
    int o0 = (w == 0) ? 0 : (w == 1) ? 9 : (w == 2) ? 18 : 26;
    int no = (w < 2) ? 9 : 8;
    float acc[9];
#pragma unroll
    for (int q = 0; q < 9; ++q) acc[q] = 0.f;
#pragma unroll
    for (int c0 = 0; c0 < 64; c0 += 32) {
      float xr[32];
#pragma unroll
      for (int c = 0; c < 32; ++c) xr[c] = preS[lane][c0 + c];
      for (int q = 0; q < 9; ++q) {
        if (q < no) {
          const float* wp = xproj_W + (o0 + q) * 64 + c0;
          float a = acc[q];
#pragma unroll
          for (int c = 0; c < 32; ++c) a = fmaf(xr[c], wp[c], a);
          acc[q] = a;
        }
      }
    }
#pragma unroll
    for (int q = 0; q < 9; ++q)
      if (q < no) xdS[lane][o0 + q] = acc[q];
  }
  __syncthreads();
  h16* SDTp = SDT2 + ((size_t)i * L_ + t0) * DI;
  for (int k = tid; k < 4096; k += 256) {
    int d = k & 63, r = k >> 6;
    float raw = fmaf(xdS[r][0], dtWS[d][0], fmaf(xdS[r][1], dtWS[d][1], dtbS[d]));
    SDTp[(size_t)r * DI + d] = (h16)softplusf_(raw);
  }
  // B|C as one contiguous f32 row per t (for scalar loads in k3a/k3c)
  float* BCp = BC2 + ((size_t)i * L_ + t0) * 32;
  for (int k = tid; k < 2048; k += 256) {
    int r = k >> 5, j = k & 31;
    BCp[r * 32 + j] = xdS[r][2 + j];
  }
}

// ---------------- K3a: per-segment local scan (LDS-free, d-per-lane) -> (P,Q) --
__global__ __launch_bounds__(256) void k3a_seg(
    const float* __restrict__ A_log, const h16* __restrict__ SDT2,
    const h16* __restrict__ SX2, const float* __restrict__ BC2,
    float* __restrict__ Pp, float* __restrict__ Qp) {
  int gw = __builtin_amdgcn_readfirstlane(blockIdx.x * 4 + (threadIdx.x >> 6));
  int i = gw >> 7;            // NSEG=128
  int seg = gw & 127;
  int lane = threadIdx.x & 63;
  int t0 = seg * SL;
  float Av[16];
#pragma unroll
  for (int s = 0; s < 16; ++s) Av[s] = -__expf(A_log[lane * 16 + s]);
  float A0 = Av[0];
  bool okf = true;
#pragma unroll
  for (int s = 0; s < 16; ++s) okf &= fabsf(Av[s] - (float)(s + 1) * A0) <= 1e-4f * fabsf(Av[s]);
  int fastp = __all(okf ? 1 : 0);
  float h[16];
#pragma unroll
  for (int s = 0; s < 16; ++s) h[s] = 0.f;
  float sdt = 0.f;
  const h16* pdt = SDT2 + ((size_t)i * L_ + t0) * DI + lane;
  const h16* pxx = SX2 + ((size_t)i * L_ + t0) * DI + lane;
  const float* pbc = BC2 + ((size_t)i * L_ + t0) * 32;
  float dtc = (float)pdt[0], xvc = (float)pxx[0];
  for (int t = 0; t < SL; ++t) {
    float dt = dtc, xv = xvc;
    if (t < SL - 1) { dtc = (float)pdt[(t + 1) * DI]; xvc = (float)pxx[(t + 1) * DI]; }
    const float* bc = pbc + t * 32;      // wave-uniform -> s_load
    float Bv[16];
#pragma unroll
    for (int j = 0; j < 4; ++j) *(float4*)&Bv[4 * j] = *(const float4*)(bc + 4 * j);
    float dtx = dt * xv;
    if (fastp) {
      float E = __expf(A0 * dt);
      float e = E;
#pragma unroll
      for (int s = 0; s < 16; ++s) {
        h[s] = fmaf(e, h[s], dtx * Bv[s]);
        e *= E;
      }
    } else {
#pragma unroll
      for (int s = 0; s < 16; ++s) h[s] = fmaf(__expf(Av[s] * dt), h[s], dtx * Bv[s]);
    }
    sdt += dt;
  }
  float P[16];
  if (fastp) {
    float E = __expf(A0 * sdt);
    float e = E;
#pragma unroll
    for (int s = 0; s < 16; ++s) { P[s] = e; e *= E; }
  } else {
#pragma unroll
    for (int s = 0; s < 16; ++s) P[s] = __expf(Av[s] * sdt);
  }
  size_t base = ((size_t)(i * NSEG + seg) * DI + lane) * DS;
#pragma unroll
  for (int j = 0; j < 4; ++j) {
    *(float4*)(Pp + base + 4 * j) = *(float4*)&P[4 * j];
    *(float4*)(Qp + base + 4 * j) = *(float4*)&h[4 * j];
  }
}

// ---------------- K3b: inter-segment scan -> h0 per segment (overlays P) -------
__global__ __launch_bounds__(256) void k3b_comb(float* __restrict__ Pp,
                                                const float* __restrict__ Qp) {
  int g = blockIdx.x * 256 + threadIdx.x;  // 32768 = NI*DI*DS
  int i = g >> 10;
  int ds = g & 1023;
  float H = 0.f;
  for (int seg = 0; seg < NSEG; ++seg) {
    size_t a = (size_t)(i * NSEG + seg) * (DI * DS) + ds;
    float P = Pp[a], Q = Qp[a];
    Pp[a] = H;
    H = fmaf(P, H, Q);
  }
}

// ---------------- K3c: final scan (LDS-free), fused z-gate/D-term/token-sums ---
__global__ __launch_bounds__(256) void k3c_scan(
    const float* __restrict__ A_log, const h16* __restrict__ SDT2,
    const h16* __restrict__ SX2, const float* __restrict__ BC2,
    const float* __restrict__ XN, const float* __restrict__ in_W,
    const float* __restrict__ D_p, const float* __restrict__ H0p,
    h16* __restrict__ YS2, float* __restrict__ SUMYF) {
  int gw = __builtin_amdgcn_readfirstlane(blockIdx.x * 4 + (threadIdx.x >> 6));
  int i = gw >> 7;
  int seg = gw & 127;
  int b = i >> 2, ch = i & 3;
  int lane = threadIdx.x & 63;
  int t0 = seg * SL;
  float Av[16];
#pragma unroll
  for (int s = 0; s < 16; ++s) Av[s] = -__expf(A_log[lane * 16 + s]);
  float A0 = Av[0];
  bool okf = true;
#pragma unroll
  for (int s = 0; s < 16; ++s) okf &= fabsf(Av[s] - (float)(s + 1) * A0) <= 1e-4f * fabsf(Av[s]);
  int fastp = __all(okf ? 1 : 0);
  float4 wz[8];
#pragma unroll
  for (int j = 0; j < 8; ++j) wz[j] = *(const float4*)(in_W + 2048 + lane * 32 + 4 * j);
  float Dp = D_p[lane];
  float h[16];
  {
    size_t base = ((size_t)(i * NSEG + seg) * DI + lane) * DS;
#pragma unroll
    for (int j = 0; j < 4; ++j) *(float4*)&h[4 * j] = *(const float4*)(H0p + base + 4 * j);
  }
  const h16* pdt = SDT2 + ((size_t)i * L_ + t0) * DI + lane;
  const h16* pxx = SX2 + ((size_t)i * L_ + t0) * DI + lane;
  const float* pbc = BC2 + ((size_t)i * L_ + t0) * 32;
  const float* pu0 = XN + ((size_t)(b * L_ + t0)) * C_ + ch * DM;
  h16* pys = YS2 + ((size_t)i * L_ + t0) * DI + lane;
  float dtc = (float)pdt[0], xvc = (float)pxx[0];
  float sum = 0.f;
  for (int t = 0; t < SL; ++t) {
    float dt = dtc, xv = xvc;
    if (t < SL - 1) { dtc = (float)pdt[(t + 1) * DI]; xvc = (float)pxx[(t + 1) * DI]; }
    const float* bc = pbc + t * 32;      // wave-uniform -> s_load
    float Bv[16], Cv[16];
#pragma unroll
    for (int j = 0; j < 4; ++j) {
      *(float4*)&Bv[4 * j] = *(const float4*)(bc + 4 * j);
      *(float4*)&Cv[4 * j] = *(const float4*)(bc + 16 + 4 * j);
    }
    float dtx = dt * xv;
    float y = 0.f;
    if (fastp) {
      float E = __expf(A0 * dt);
      float e = E;
#pragma unroll
      for (int s = 0; s < 16; ++s) {
        h[s] = fmaf(e, h[s], dtx * Bv[s]);
        y = fmaf(h[s], Cv[s], y);
        e *= E;
      }
    } else {
#pragma unroll
      for (int s = 0; s < 16; ++s) {
        h[s] = fmaf(__expf(Av[s] * dt), h[s], dtx * Bv[s]);
        y = fmaf(h[s], Cv[s], y);
      }
    }
    // z-gate: u row is wave-uniform -> s_load
    const float* pu = pu0 + (size_t)t * C_;
    float z = 0.f;
#pragma unroll
    for (int j = 0; j < 8; ++j) {
      float4 u4 = *(const float4*)(pu + 4 * j);
      z = fmaf(u4.x, wz[j].x, z);
      z = fmaf(u4.y, wz[j].y, z);
      z = fmaf(u4.z, wz[j].z, z);
      z = fmaf(u4.w, wz[j].w, z);
    }
    float yf = (y + xv * Dp) * siluf_(z);
    pys[(size_t)t * DI] = (h16)yf;
    sum += yf;
  }
  atomicAdd(&SUMYF[i * DI + lane], sum);
}

// ---------------- K4: SE gates ----------------
__global__ __launch_bounds__(64) void k4_gates(
    const float* __restrict__ out_W, const float* __restrict__ se_W1,
    const float* __restrict__ se_W2, const float* __restrict__ skip_p,
    const float* __restrict__ SUMYF, const float* __restrict__ SUMXN,
    float* __restrict__ GATES) {
  int i = blockIdx.x;
  int b = i >> 2, ch = i & 3;
  int tid = threadIdx.x;
  __shared__ float syS[64], catS[64], seS[2];
  syS[tid] = SUMYF[i * DI + tid];
  __syncthreads();
  float invL = 1.f / (float)L_;
  if (tid < 32) {
    float acc = 0.f;
#pragma unroll
    for (int dd = 0; dd < 64; ++dd) acc = fmaf(syS[dd], out_W[tid * 64 + dd], acc);
    catS[tid] = acc * invL;
  } else {
    int c = tid - 32;
    catS[tid] = skip_p[0] * SUMXN[b * C_ + ch * DM + c] * invL;
  }
  __syncthreads();
  if (tid < 2) {
    float acc = 0.f;
#pragma unroll
    for (int k = 0; k < 64; ++k) acc = fmaf(catS[k], se_W1[tid * 64 + k], acc);
    seS[tid] = fmaxf(acc, 0.f);
  }
  __syncthreads();
  float gg = fmaf(seS[0], se_W2[tid * 2 + 0], seS[1] * se_W2[tid * 2 + 1]);
  GATES[i * DI + tid] = sigmoidf_(gg);
}

// ---------------- K5b: M1 = yfull @ outW.T, gated combine (in place over xn) ---
__global__ __launch_bounds__(256) void k5b_combine(
    const float* __restrict__ out_W, const float* __restrict__ skip_p,
    const float* __restrict__ GATES, const h16* __restrict__ YS2,
    float* __restrict__ XN) {
  int bid = blockIdx.x;
  int i = bid >> 6, tile = bid & 63;
  int b = i >> 2, ch = i & 3;
  int t0 = tile * 64;
  int tid = threadIdx.x;
  int w = tid >> 6, lane = tid & 63;
  __shared__ float outWS[32][68];
  __shared__ float yfT[64][65];
  __shared__ float xnS[64][37];
  __shared__ float gS[64];
  for (int k = tid; k < 2048; k += 256) outWS[k >> 6][k & 63] = out_W[k];
  if (tid < 64) gS[tid] = GATES[i * DI + tid];
  const h16* py = YS2 + ((size_t)i * L_ + t0) * DI;
  for (int k = tid; k < 4096; k += 256) {
    int dd = k & 63, tt = k >> 6;
    yfT[tt][dd] = (float)py[(size_t)tt * DI + dd];
  }
  float* xn = XN + (size_t)b * L_ * C_ + ch * DM;
  for (int k = tid; k < 2048; k += 256) {
    int tt = k >> 5, o = k & 31;
    xnS[tt][o] = xn[(size_t)(t0 + tt) * C_ + o];
  }
  __syncthreads();
  float yr[64];
#pragma unroll
  for (int dd = 0; dd < 64; ++dd) yr[dd] = yfT[lane][dd];
  float skip = skip_p[0];
#pragma unroll
  for (int q = 0; q < 8; ++q) {
    int o = w * 8 + q;
    float a = 0.f;
#pragma unroll
    for (int d4 = 0; d4 < 64; d4 += 4) {
      float4 wv = *(const float4*)&outWS[o][d4];
      a = fmaf(yr[d4], wv.x, a);
      a = fmaf(yr[d4 + 1], wv.y, a);
      a = fmaf(yr[d4 + 2], wv.z, a);
      a = fmaf(yr[d4 + 3], wv.w, a);
    }
    xnS[lane][o] = gS[o] * a + gS[32 + o] * skip * xnS[lane][o];
  }
  __syncthreads();
  for (int k = tid; k < 2048; k += 256) {
    int tt = k >> 5, o = k & 31;
    xn[(size_t)(t0 + tt) * C_ + o] = xnS[tt][o];
  }
}

// ---------------- K6: LN2 + proj + transpose to (B,OUT,H,W) ----------------
__global__ __launch_bounds__(256) void k6_ln_proj(
    const float* __restrict__ gn, const float* __restrict__ bn,
    const float* __restrict__ proj_W, const float* __restrict__ proj_b,
    const float* __restrict__ XN, float* __restrict__ out) {
  int bid = blockIdx.x;
  int b = bid >> 6, tile = bid & 63;
  int t0 = tile * 64;
  int tid = threadIdx.x;
  int w = tid >> 6, lane = tid & 63;
  __shared__ float xmS[64][132];
  __shared__ float projS[64][132];
  __shared__ float gnS[128], bnS[128];
  if (tid < 128) { gnS[tid] = gn[tid]; bnS[tid] = bn[tid]; }
  const float* xm = XN + (size_t)b * L_ * C_;
  for (int k = tid; k < 8192; k += 256) {
    int tt = k >> 7, c = k & 127;
    xmS[tt][c] = xm[(size_t)(t0 + tt) * C_ + c];
  }
  for (int k = tid; k < 8192; k += 256) {
    int o = k >> 7, c = k & 127;
    projS[o][c] = proj_W[k];
  }
  __syncthreads();
  {
    int tok = tid >> 2, q = tid & 3;
    float s = 0.f, qq = 0.f;
#pragma unroll
    for (int j = 0; j < 32; ++j) {
      float v = xmS[tok][4 * j + q];
      s += v; qq += v * v;
    }
    s = dpp_add_<0xB1>(s); qq = dpp_add_<0xB1>(qq);
    s = dpp_add_<0x4E>(s); qq = dpp_add_<0x4E>(qq);
    float m = s * (1.f / 128.f);
    float var = qq * (1.f / 128.f) - m * m;
    float rs = rsqrtf(var + 1e-5f);
#pragma unroll
    for (int j = 0; j < 32; ++j) {
      int c = 4 * j + q;
      float v = xmS[tok][c];
      xmS[tok][c] = (v - m) * rs * gnS[c] + bnS[c];
    }
  }
  __syncthreads();
  int lt = lane >> 2, lo = lane & 3;
  for (int phase = 0; phase < 2; ++phase) {
    if (phase == 1) {
      __syncthreads();
      for (int k = tid; k < 8192; k += 256) {
        int o = k >> 7, c = k & 127;
        projS[o][c] = proj_W[8192 + k];
      }
      __syncthreads();
    }
    int obase = phase * 64 + w * 16 + lo * 4;
    float acc[16];
#pragma unroll
    for (int j = 0; j < 4; ++j)
#pragma unroll
      for (int oi = 0; oi < 4; ++oi) acc[j * 4 + oi] = proj_b[obase + oi];
#pragma unroll 4
    for (int c0 = 0; c0 < 128; c0 += 4) {
      float4 xr[4], pr[4];
#pragma unroll
      for (int j = 0; j < 4; ++j) xr[j] = *(const float4*)&xmS[lt * 4 + j][c0];
#pragma unroll
      for (int oi = 0; oi < 4; ++oi) pr[oi] = *(const float4*)&projS[w * 16 + lo * 4 + oi][c0];
#pragma unroll
      for (int j = 0; j < 4; ++j)
#pragma unroll
        for (int oi = 0; oi < 4; ++oi) {
          float a = acc[j * 4 + oi];
          a = fmaf(xr[j].x, pr[oi].x, a);
          a = fmaf(xr[j].y, pr[oi].y, a);
          a = fmaf(xr[j].z, pr[oi].z, a);
          a = fmaf(xr[j].w, pr[oi].w, a);
          acc[j * 4 + oi] = a;
        }
    }
#pragma unroll
    for (int oi = 0; oi < 4; ++oi) {
      int o = obase + oi;
      float4 v = make_float4(acc[0 * 4 + oi], acc[1 * 4 + oi],
                             acc[2 * 4 + oi], acc[3 * 4 + oi]);
      *(float4*)&out[((size_t)(b * OUT_ + o)) * L_ + t0 + lt * 4] = v;
    }
  }
}

extern "C" void kernel_launch(void* const* d_in, const int* in_sizes, int n_in,
                              void* d_out, int out_size, void* d_ws, size_t ws_size,
                              hipStream_t stream) {
  const float* x = (const float*)d_in[0];
  const float* norm_g = (const float*)d_in[1];
  const float* norm_b = (const float*)d_in[2];
  const float* proj_W = (const float*)d_in[3];
  const float* proj_b = (const float*)d_in[4];
  const float* skip = (const float*)d_in[5];
  const float* se_W1 = (const float*)d_in[6];
  const float* se_W2 = (const float*)d_in[7];
  const float* in_W = (const float*)d_in[8];
  const float* conv_W = (const float*)d_in[9];
  const float* conv_b = (const float*)d_in[10];
  const float* xproj_W = (const float*)d_in[11];
  const float* dt_W = (const float*)d_in[12];
  const float* dt_b = (const float*)d_in[13];
  const float* A_log = (const float*)d_in[14];
  const float* D_p = (const float*)d_in[15];
  const float* out_W = (const float*)d_in[16];
  float* out = (float*)d_out;

  // workspace (~101 MiB). YS2 aliases Qp: k3a writes Q, k3b consumes Q,
  // then k3c writes YS2 over it (k3c never reads Q); k5b reads YS2 after.
  float* XN = (float*)d_ws;                         // B*L*C f32
  float* SUMYF = XN + (size_t)B_ * L_ * C_;         // NI*DI
  float* SUMXN = SUMYF + NI * DI;                   // B*C
  float* GATES = SUMXN + B_ * C_;                   // NI*DI
  float* Pp = GATES + NI * DI;                      // NI*NSEG*DI*DS f32
  float* Qp = Pp + (size_t)NI * NSEG * DI * DS;     // NI*NSEG*DI*DS f32
  float* BC2 = Qp + (size_t)NI * NSEG * DI * DS;    // NI*L*32 f32
  h16* YS2 = (h16*)Qp;                              // alias (same byte size)
  h16* SX2 = (h16*)(BC2 + (size_t)NI * L_ * 32);    // NI*L*DI h16
  h16* SDT2 = SX2 + (size_t)NI * L_ * DI;           // NI*L*DI h16

  hipMemsetAsync(SUMYF, 0, (size_t)(NI * DI + B_ * C_) * sizeof(float), stream);
  k1_ln<<<B_ * 64, 256, 0, stream>>>(x, norm_g, norm_b, XN, SUMXN);
  k2_prep<<<NI * 64, 256, 0, stream>>>(in_W, conv_W, conv_b, xproj_W, dt_W, dt_b,
                                       XN, SX2, SDT2, BC2);
  k3a_seg<<<NI * NSEG / 4, 256, 0, stream>>>(A_log, SDT2, SX2, BC2, Pp, Qp);
  k3b_comb<<<128, 256, 0, stream>>>(Pp, Qp);
  k3c_scan<<<NI * NSEG / 4, 256, 0, stream>>>(A_log, SDT2, SX2, BC2, XN, in_W, D_p,
                                              Pp, YS2, SUMYF);
  k4_gates<<<NI, 64, 0, stream>>>(out_W, se_W1, se_W2, skip, SUMYF, SUMXN, GATES);
  k5b_combine<<<NI * 64, 256, 0, stream>>>(out_W, skip, GATES, YS2, XN);
  k6_ln_proj<<<B_ * 64, 256, 0, stream>>>(norm_g, norm_b, proj_W, proj_b, XN, out);
}

// Round 8
// 298.167 us; speedup vs baseline: 1.0094x; 1.0094x over previous
//
#include <hip/hip_runtime.h>
#include <math.h>

typedef _Float16 h16;

#define DEV static __device__ __forceinline__

constexpr int B_ = 8, C_ = 128, L_ = 4096, OUT_ = 128;
constexpr int NCH = 4, DM = 32, DS = 16, DI = 64;
constexpr int NI = 32;            // B_*NCH instances
constexpr int NSEG = 128;         // scan segments
constexpr int SL = L_ / NSEG;     // 32 steps per segment

DEV float sigmoidf_(float x) { return 1.f / (1.f + __expf(-x)); }
DEV float siluf_(float x) { return x * sigmoidf_(x); }
DEV float softplusf_(float x) { return (x > 20.f) ? x : __logf(1.f + __expf(x)); }

template <int CTRL>
DEV float dpp_add_(float x) {
  int v = __builtin_amdgcn_update_dpp(0, __float_as_int(x), CTRL, 0xf, 0xf, false);
  return x + __int_as_float(v);
}

// ---- K2 (fused LN1 + in-proj + conv + silu + x-proj + dt), t-major outputs ----
__global__ __launch_bounds__(256) void k2_prep(
    const float* __restrict__ x, const float* __restrict__ gn,
    const float* __restrict__ bn, const float* __restrict__ in_W,
    const float* __restrict__ conv_W, const float* __restrict__ conv_b,
    const float* __restrict__ xproj_W, const float* __restrict__ dt_W,
    const float* __restrict__ dt_b, float* __restrict__ XN,
    float* __restrict__ SUMXN, h16* __restrict__ SX2, h16* __restrict__ SDT2,
    float* __restrict__ BC2) {
  int bid = blockIdx.x;
  int i = bid >> 6, tile = bid & 63;
  int b = i >> 2, ch = i & 3;
  int t0 = tile * 64;
  int tid = threadIdx.x;
  int w = __builtin_amdgcn_readfirstlane(tid >> 6);
  int lane = tid & 63;

  // region A: xT (h16 128x74 = 18.9 KB) reused as preS(67x65 f32)+xdS(64x35 f32)
  __shared__ __align__(16) float smemA[67 * 65 + 64 * 35];
  h16 (*xT)[74] = (h16(*)[74])smemA;
  float (*preS)[65] = (float(*)[65])smemA;
  float (*xdS)[35] = (float(*)[35])(smemA + 67 * 65);
  __shared__ float uS[67][33];
  __shared__ float mS[68], rsS[68];
  __shared__ float gnS[32], bnS[32];
  __shared__ float convWS[64][4];
  __shared__ float dtWS[64][2];
  __shared__ float dtbS[64], cbS[64];
  __shared__ float red[256];

  convWS[tid >> 2][tid & 3] = conv_W[tid];
  if (tid < 128) dtWS[tid >> 1][tid & 1] = dt_W[tid];
  if (tid < 64) { dtbS[tid] = dt_b[tid]; cbS[tid] = conv_b[tid]; }
  if (tid < 32) { gnS[tid] = gn[ch * 32 + tid]; bnS[tid] = bn[ch * 32 + tid]; }
  // load x tile (coalesced along L): rows 3..66 = tokens t0..t0+63
  const float* xb = x + (size_t)b * C_ * L_;
  for (int k = tid; k < 8192; k += 256) {
    int c = k >> 6, tt = k & 63;
    xT[c][tt + 3] = (h16)xb[(size_t)c * L_ + t0 + tt];
  }
  if (tid < 128) {
#pragma unroll
    for (int j = 0; j < 3; ++j) {
      int tg = t0 - 3 + j;
      xT[tid][j] = (tg >= 0) ? (h16)xb[(size_t)tid * L_ + tg] : (h16)0.f;
    }
  }
  __syncthreads();
  // LN stats (rows 0..63 by 4 threads/row; rows 64..66 by tid<12)
  {
    int tok = tid >> 2, q = tid & 3;
    float s = 0.f, qq = 0.f;
#pragma unroll
    for (int j = 0; j < 32; ++j) {
      float v = (float)xT[q + 4 * j][tok];
      s += v; qq += v * v;
    }
    s = dpp_add_<0xB1>(s); qq = dpp_add_<0xB1>(qq);
    s = dpp_add_<0x4E>(s); qq = dpp_add_<0x4E>(qq);
    if (q == 0) {
      float m = s * (1.f / 128.f);
      mS[tok] = m;
      rsS[tok] = rsqrtf(qq * (1.f / 128.f) - m * m + 1e-5f);
    }
    if (tid < 12) {
      int tok2 = 64 + (tid >> 2);
      float s2 = 0.f, q2 = 0.f;
#pragma unroll
      for (int j = 0; j < 32; ++j) {
        float v = (float)xT[(tid & 3) + 4 * j][tok2];
        s2 += v; q2 += v * v;
      }
      s2 = dpp_add_<0xB1>(s2); q2 = dpp_add_<0xB1>(q2);
      s2 = dpp_add_<0x4E>(s2); q2 = dpp_add_<0x4E>(q2);
      if ((tid & 3) == 0) {
        float m = s2 * (1.f / 128.f);
        mS[tok2] = m;
        rsS[tok2] = rsqrtf(q2 * (1.f / 128.f) - m * m + 1e-5f);
      }
    }
  }
  __syncthreads();
  // normalize this chunk's 32-c slice -> uS (rows 0..66); zero for t<0
  for (int k = tid; k < 67 * 32; k += 256) {
    int tt = k >> 5, c = k & 31;
    int tg = t0 - 3 + tt;
    float u = 0.f;
    if (tg >= 0) {
      float v = (float)xT[ch * 32 + c][tt];
      u = (v - mS[tt]) * rsS[tt] * gnS[c] + bnS[c];
    }
    uS[tt][c] = u;
  }
  __syncthreads();   // xT dead -> preS/xdS region free
  // XN slice writeout + token-sum partials (rows 3..66)
  {
    float acc = 0.f;
    for (int k = tid; k < 2048; k += 256) {
      int tt = k >> 5, c = k & 31;
      float v = uS[tt + 3][c];
      XN[((size_t)(b * L_ + t0 + tt)) * C_ + ch * 32 + c] = v;
      acc += v;
    }
    red[tid] = acc;
  }
  // in-proj main: ur in regs, weights via uniform float4 (s_load), 2 accums
  float ur[32];
#pragma unroll
  for (int c = 0; c < 32; ++c) ur[c] = uS[lane][c];
  {
    int d0 = w * 16;
#pragma unroll
    for (int q = 0; q < 16; ++q) {
      int d = d0 + q;
      const float4* wp4 = (const float4*)(in_W + d * 32);
      float a0 = 0.f, a1 = 0.f;
#pragma unroll
      for (int j = 0; j < 4; ++j) {
        float4 f = wp4[j];
        a0 = fmaf(ur[4 * j], f.x, a0);
        a0 = fmaf(ur[4 * j + 1], f.y, a0);
        a0 = fmaf(ur[4 * j + 2], f.z, a0);
        a0 = fmaf(ur[4 * j + 3], f.w, a0);
      }
#pragma unroll
      for (int j = 4; j < 8; ++j) {
        float4 f = wp4[j];
        a1 = fmaf(ur[4 * j], f.x, a1);
        a1 = fmaf(ur[4 * j + 1], f.y, a1);
        a1 = fmaf(ur[4 * j + 2], f.z, a1);
        a1 = fmaf(ur[4 * j + 3], f.w, a1);
      }
      preS[lane][d] = a0 + a1;
    }
  }
  if (w < 3) {   // halo rows 64..66 (d = lane, per-lane weights, L2-hot)
    int rh = 64 + w;
    const float* wp = in_W + lane * 32;
    float a = 0.f;
#pragma unroll
    for (int c = 0; c < 32; ++c) a = fmaf(uS[rh][c], wp[c], a);
    preS[rh][lane] = a;
  }
  __syncthreads();
  if (tid < 32) {   // finish SUMXN
    float s = 0.f;
#pragma unroll
    for (int j = 0; j < 8; ++j) s += red[tid + 32 * j];
    atomicAdd(&SUMXN[b * C_ + ch * 32 + tid], s);
  }
  // causal depthwise conv + silu
  float convv[16];
  {
    int idx = 0;
    for (int k = tid; k < 4096; k += 256, ++idx) {
      int r = k >> 6, d = k & 63;
      float v = cbS[d];
#pragma unroll
      for (int j = 0; j < 4; ++j) v = fmaf(convWS[d][j], preS[r + j][d], v);
      convv[idx] = siluf_(v);
    }
  }
  __syncthreads();
  {
    int idx = 0;
    for (int k = tid; k < 4096; k += 256, ++idx) {
      int r = k >> 6, d = k & 63;
      preS[r][d] = convv[idx];
    }
  }
  __syncthreads();
  h16* SXp = SX2 + ((size_t)i * L_ + t0) * DI;
  for (int k = tid; k < 4096; k += 256) {
    int d = k & 63, r = k >> 6;
    SXp[(size_t)r * DI + d] = (h16)preS[r][d];
  }
  // x-proj: 8 outputs/wave + 2 tail outputs on waves 0,1 (no inner conditional)
  {
    float acc[8];
    float accx = 0.f;
    int o0 = w * 8;
    int ox = 32 + w;
#pragma unroll
    for (int q = 0; q < 8; ++q) acc[q] = 0.f;
#pragma unroll
    for (int c0 = 0; c0 < 64; c0 += 32) {
      float xr[32];
#pragma unroll
      for (int c = 0; c < 32; ++c) xr[c] = preS[lane][c0 + c];
#pragma unroll
      for (int q = 0; q < 8; ++q) {
        const float4* wp4 = (const float4*)(xproj_W + (o0 + q) * 64 + c0);
        float a = acc[q];
#pragma unroll
        for (int j = 0; j < 8; ++j) {
          float4 f = wp4[j];
          a = fmaf(xr[4 * j], f.x, a);
          a = fmaf(xr[4 * j + 1], f.y, a);
          a = fmaf(xr[4 * j + 2], f.z, a);
          a = fmaf(xr[4 * j + 3], f.w, a);
        }
        acc[q] = a;
      }
      if (w < 2) {
        const float4* wp4 = (const float4*)(xproj_W + ox * 64 + c0);
#pragma unroll
        for (int j = 0; j < 8; ++j) {
          float4 f = wp4[j];
          accx = fmaf(xr[4 * j], f.x, accx);
          accx = fmaf(xr[4 * j + 1], f.y, accx);
          accx = fmaf(xr[4 * j + 2], f.z, accx);
          accx = fmaf(xr[4 * j + 3], f.w, accx);
        }
      }
    }
#pragma unroll
    for (int q = 0; q < 8; ++q) xdS[lane][o0 + q] = acc[q];
    if (w < 2) xdS[lane][ox] = accx;
  }
  __syncthreads();
  h16* SDTp = SDT2 + ((size_t)i * L_ + t0) * DI;
  for (int k = tid; k < 4096; k += 256) {
    int d = k & 63, r = k >> 6;
    float raw = fmaf(xdS[r][0], dtWS[d][0], fmaf(xdS[r][1], dtWS[d][1], dtbS[d]));
    SDTp[(size_t)r * DI + d] = (h16)softplusf_(raw);
  }
  float* BCp = BC2 + ((size_t)i * L_ + t0) * 32;
  for (int k = tid; k < 2048; k += 256) {
    int r = k >> 5, j = k & 31;
    BCp[r * 32 + j] = xdS[r][2 + j];
  }
}

// ---------------- K3a: per-segment local scan (LDS-free, d-per-lane) -> (P,Q) --
__global__ __launch_bounds__(256) void k3a_seg(
    const float* __restrict__ A_log, const h16* __restrict__ SDT2,
    const h16* __restrict__ SX2, const float* __restrict__ BC2,
    float* __restrict__ Pp, float* __restrict__ Qp) {
  int gw = __builtin_amdgcn_readfirstlane(blockIdx.x * 4 + (threadIdx.x >> 6));
  int i = gw >> 7;            // NSEG=128
  int seg = gw & 127;
  int lane = threadIdx.x & 63;
  int t0 = seg * SL;
  float Av[16];
#pragma unroll
  for (int s = 0; s < 16; ++s) Av[s] = -__expf(A_log[lane * 16 + s]);
  float A0 = Av[0];
  bool okf = true;
#pragma unroll
  for (int s = 0; s < 16; ++s) okf &= fabsf(Av[s] - (float)(s + 1) * A0) <= 1e-4f * fabsf(Av[s]);
  int fastp = __all(okf ? 1 : 0);
  float h[16];
#pragma unroll
  for (int s = 0; s < 16; ++s) h[s] = 0.f;
  float sdt = 0.f;
  const h16* pdt = SDT2 + ((size_t)i * L_ + t0) * DI + lane;
  const h16* pxx = SX2 + ((size_t)i * L_ + t0) * DI + lane;
  const float* pbc = BC2 + ((size_t)i * L_ + t0) * 32;
  float dtc = (float)pdt[0], xvc = (float)pxx[0];
  for (int t = 0; t < SL; ++t) {
    float dt = dtc, xv = xvc;
    if (t < SL - 1) { dtc = (float)pdt[(t + 1) * DI]; xvc = (float)pxx[(t + 1) * DI]; }
    const float* bc = pbc + t * 32;      // wave-uniform -> s_load
    float Bv[16];
#pragma unroll
    for (int j = 0; j < 4; ++j) *(float4*)&Bv[4 * j] = *(const float4*)(bc + 4 * j);
    float dtx = dt * xv;
    if (fastp) {
      float E = __expf(A0 * dt);
      float e = E;
#pragma unroll
      for (int s = 0; s < 16; ++s) {
        h[s] = fmaf(e, h[s], dtx * Bv[s]);
        e *= E;
      }
    } else {
#pragma unroll
      for (int s = 0; s < 16; ++s) h[s] = fmaf(__expf(Av[s] * dt), h[s], dtx * Bv[s]);
    }
    sdt += dt;
  }
  float P[16];
  if (fastp) {
    float E = __expf(A0 * sdt);
    float e = E;
#pragma unroll
    for (int s = 0; s < 16; ++s) { P[s] = e; e *= E; }
  } else {
#pragma unroll
    for (int s = 0; s < 16; ++s) P[s] = __expf(Av[s] * sdt);
  }
  size_t base = ((size_t)(i * NSEG + seg) * DI + lane) * DS;
#pragma unroll
  for (int j = 0; j < 4; ++j) {
    *(float4*)(Pp + base + 4 * j) = *(float4*)&P[4 * j];
    *(float4*)(Qp + base + 4 * j) = *(float4*)&h[4 * j];
  }
}

// ---------------- K3b: inter-segment scan -> h0 per segment (overlays P) -------
__global__ __launch_bounds__(256) void k3b_comb(float* __restrict__ Pp,
                                                const float* __restrict__ Qp) {
  int g = blockIdx.x * 256 + threadIdx.x;  // 32768 = NI*DI*DS
  int i = g >> 10;
  int ds = g & 1023;
  float H = 0.f;
  for (int seg = 0; seg < NSEG; ++seg) {
    size_t a = (size_t)(i * NSEG + seg) * (DI * DS) + ds;
    float P = Pp[a], Q = Qp[a];
    Pp[a] = H;
    H = fmaf(P, H, Q);
  }
}

// ---------------- K3c: final scan (LDS-free), fused z-gate/D-term/token-sums ---
__global__ __launch_bounds__(256) void k3c_scan(
    const float* __restrict__ A_log, const h16* __restrict__ SDT2,
    const h16* __restrict__ SX2, const float* __restrict__ BC2,
    const float* __restrict__ XN, const float* __restrict__ in_W,
    const float* __restrict__ D_p, const float* __restrict__ H0p,
    h16* __restrict__ YS2, float* __restrict__ SUMYF) {
  int gw = __builtin_amdgcn_readfirstlane(blockIdx.x * 4 + (threadIdx.x >> 6));
  int i = gw >> 7;
  int seg = gw & 127;
  int b = i >> 2, ch = i & 3;
  int lane = threadIdx.x & 63;
  int t0 = seg * SL;
  float Av[16];
#pragma unroll
  for (int s = 0; s < 16; ++s) Av[s] = -__expf(A_log[lane * 16 + s]);
  float A0 = Av[0];
  bool okf = true;
#pragma unroll
  for (int s = 0; s < 16; ++s) okf &= fabsf(Av[s] - (float)(s + 1) * A0) <= 1e-4f * fabsf(Av[s]);
  int fastp = __all(okf ? 1 : 0);
  float4 wz[8];
#pragma unroll
  for (int j = 0; j < 8; ++j) wz[j] = *(const float4*)(in_W + 2048 + lane * 32 + 4 * j);
  float Dp = D_p[lane];
  float h[16];
  {
    size_t base = ((size_t)(i * NSEG + seg) * DI + lane) * DS;
#pragma unroll
    for (int j = 0; j < 4; ++j) *(float4*)&h[4 * j] = *(const float4*)(H0p + base + 4 * j);
  }
  const h16* pdt = SDT2 + ((size_t)i * L_ + t0) * DI + lane;
  const h16* pxx = SX2 + ((size_t)i * L_ + t0) * DI + lane;
  const float* pbc = BC2 + ((size_t)i * L_ + t0) * 32;
  const float* pu0 = XN + ((size_t)(b * L_ + t0)) * C_ + ch * DM;
  h16* pys = YS2 + ((size_t)i * L_ + t0) * DI + lane;
  float dtc = (float)pdt[0], xvc = (float)pxx[0];
  float sum = 0.f;
  for (int t = 0; t < SL; ++t) {
    float dt = dtc, xv = xvc;
    if (t < SL - 1) { dtc = (float)pdt[(t + 1) * DI]; xvc = (float)pxx[(t + 1) * DI]; }
    const float* bc = pbc + t * 32;      // wave-uniform -> s_load
    float Bv[16], Cv[16];
#pragma unroll
    for (int j = 0; j < 4; ++j) {
      *(float4*)&Bv[4 * j] = *(const float4*)(bc + 4 * j);
      *(float4*)&Cv[4 * j] = *(const float4*)(bc + 16 + 4 * j);
    }
    float dtx = dt * xv;
    float y = 0.f;
    if (fastp) {
      float E = __expf(A0 * dt);
      float e = E;
#pragma unroll
      for (int s = 0; s < 16; ++s) {
        h[s] = fmaf(e, h[s], dtx * Bv[s]);
        y = fmaf(h[s], Cv[s], y);
        e *= E;
      }
    } else {
#pragma unroll
      for (int s = 0; s < 16; ++s) {
        h[s] = fmaf(__expf(Av[s] * dt), h[s], dtx * Bv[s]);
        y = fmaf(h[s], Cv[s], y);
      }
    }
    const float* pu = pu0 + (size_t)t * C_;
    float z = 0.f;
#pragma unroll
    for (int j = 0; j < 8; ++j) {
      float4 u4 = *(const float4*)(pu + 4 * j);
      z = fmaf(u4.x, wz[j].x, z);
      z = fmaf(u4.y, wz[j].y, z);
      z = fmaf(u4.z, wz[j].z, z);
      z = fmaf(u4.w, wz[j].w, z);
    }
    float yf = (y + xv * Dp) * siluf_(z);
    pys[(size_t)t * DI] = (h16)yf;
    sum += yf;
  }
  atomicAdd(&SUMYF[i * DI + lane], sum);
}

// ---------------- K4: SE gates ----------------
__global__ __launch_bounds__(64) void k4_gates(
    const float* __restrict__ out_W, const float* __restrict__ se_W1,
    const float* __restrict__ se_W2, const float* __restrict__ skip_p,
    const float* __restrict__ SUMYF, const float* __restrict__ SUMXN,
    float* __restrict__ GATES) {
  int i = blockIdx.x;
  int b = i >> 2, ch = i & 3;
  int tid = threadIdx.x;
  __shared__ float syS[64], catS[64], seS[2];
  syS[tid] = SUMYF[i * DI + tid];
  __syncthreads();
  float invL = 1.f / (float)L_;
  if (tid < 32) {
    float acc = 0.f;
#pragma unroll
    for (int dd = 0; dd < 64; ++dd) acc = fmaf(syS[dd], out_W[tid * 64 + dd], acc);
    catS[tid] = acc * invL;
  } else {
    int c = tid - 32;
    catS[tid] = skip_p[0] * SUMXN[b * C_ + ch * DM + c] * invL;
  }
  __syncthreads();
  if (tid < 2) {
    float acc = 0.f;
#pragma unroll
    for (int k = 0; k < 64; ++k) acc = fmaf(catS[k], se_W1[tid * 64 + k], acc);
    seS[tid] = fmaxf(acc, 0.f);
  }
  __syncthreads();
  float gg = fmaf(seS[0], se_W2[tid * 2 + 0], seS[1] * se_W2[tid * 2 + 1]);
  GATES[i * DI + tid] = sigmoidf_(gg);
}

// ---------------- K5b: M1 = yfull @ outW.T, gated combine (in place over xn) ---
__global__ __launch_bounds__(256) void k5b_combine(
    const float* __restrict__ out_W, const float* __restrict__ skip_p,
    const float* __restrict__ GATES, const h16* __restrict__ YS2,
    float* __restrict__ XN) {
  int bid = blockIdx.x;
  int i = bid >> 6, tile = bid & 63;
  int b = i >> 2, ch = i & 3;
  int t0 = tile * 64;
  int tid = threadIdx.x;
  int w = tid >> 6, lane = tid & 63;
  __shared__ float outWS[32][68];
  __shared__ float yfT[64][65];
  __shared__ float xnS[64][37];
  __shared__ float gS[64];
  for (int k = tid; k < 2048; k += 256) outWS[k >> 6][k & 63] = out_W[k];
  if (tid < 64) gS[tid] = GATES[i * DI + tid];
  const h16* py = YS2 + ((size_t)i * L_ + t0) * DI;
  for (int k = tid; k < 4096; k += 256) {
    int dd = k & 63, tt = k >> 6;
    yfT[tt][dd] = (float)py[(size_t)tt * DI + dd];
  }
  float* xn = XN + (size_t)b * L_ * C_ + ch * DM;
  for (int k = tid; k < 2048; k += 256) {
    int tt = k >> 5, o = k & 31;
    xnS[tt][o] = xn[(size_t)(t0 + tt) * C_ + o];
  }
  __syncthreads();
  float yr[64];
#pragma unroll
  for (int dd = 0; dd < 64; ++dd) yr[dd] = yfT[lane][dd];
  float skip = skip_p[0];
#pragma unroll
  for (int q = 0; q < 8; ++q) {
    int o = w * 8 + q;
    float a = 0.f;
#pragma unroll
    for (int d4 = 0; d4 < 64; d4 += 4) {
      float4 wv = *(const float4*)&outWS[o][d4];
      a = fmaf(yr[d4], wv.x, a);
      a = fmaf(yr[d4 + 1], wv.y, a);
      a = fmaf(yr[d4 + 2], wv.z, a);
      a = fmaf(yr[d4 + 3], wv.w, a);
    }
    xnS[lane][o] = gS[o] * a + gS[32 + o] * skip * xnS[lane][o];
  }
  __syncthreads();
  for (int k = tid; k < 2048; k += 256) {
    int tt = k >> 5, o = k & 31;
    xn[(size_t)(t0 + tt) * C_ + o] = xnS[tt][o];
  }
}

// ---------------- K6: LN2 + proj + transpose to (B,OUT,H,W) ----------------
__global__ __launch_bounds__(256) void k6_ln_proj(
    const float* __restrict__ gn, const float* __restrict__ bn,
    const float* __restrict__ proj_W, const float* __restrict__ proj_b,
    const float* __restrict__ XN, float* __restrict__ out) {
  int bid = blockIdx.x;
  int b = bid >> 6, tile = bid & 63;
  int t0 = tile * 64;
  int tid = threadIdx.x;
  int w = tid >> 6, lane = tid & 63;
  __shared__ float xmS[64][132];
  __shared__ float projS[64][132];
  __shared__ float gnS[128], bnS[128];
  if (tid < 128) { gnS[tid] = gn[tid]; bnS[tid] = bn[tid]; }
  const float* xm = XN + (size_t)b * L_ * C_;
  for (int k = tid; k < 8192; k += 256) {
    int tt = k >> 7, c = k & 127;
    xmS[tt][c] = xm[(size_t)(t0 + tt) * C_ + c];
  }
  for (int k = tid; k < 8192; k += 256) {
    int o = k >> 7, c = k & 127;
    projS[o][c] = proj_W[k];
  }
  __syncthreads();
  {
    int tok = tid >> 2, q = tid & 3;
    float s = 0.f, qq = 0.f;
#pragma unroll
    for (int j = 0; j < 32; ++j) {
      float v = xmS[tok][4 * j + q];
      s += v; qq += v * v;
    }
    s = dpp_add_<0xB1>(s); qq = dpp_add_<0xB1>(qq);
    s = dpp_add_<0x4E>(s); qq = dpp_add_<0x4E>(qq);
    float m = s * (1.f / 128.f);
    float var = qq * (1.f / 128.f) - m * m;
    float rs = rsqrtf(var + 1e-5f);
#pragma unroll
    for (int j = 0; j < 32; ++j) {
      int c = 4 * j + q;
      float v = xmS[tok][c];
      xmS[tok][c] = (v - m) * rs * gnS[c] + bnS[c];
    }
  }
  __syncthreads();
  int lt = lane >> 2, lo = lane & 3;
  for (int phase = 0; phase < 2; ++phase) {
    if (phase == 1) {
      __syncthreads();
      for (int k = tid; k < 8192; k += 256) {
        int o = k >> 7, c = k & 127;
        projS[o][c] = proj_W[8192 + k];
      }
      __syncthreads();
    }
    int obase = phase * 64 + w * 16 + lo * 4;
    float acc[16];
#pragma unroll
    for (int j = 0; j < 4; ++j)
#pragma unroll
      for (int oi = 0; oi < 4; ++oi) acc[j * 4 + oi] = proj_b[obase + oi];
#pragma unroll 4
    for (int c0 = 0; c0 < 128; c0 += 4) {
      float4 xr[4], pr[4];
#pragma unroll
      for (int j = 0; j < 4; ++j) xr[j] = *(const float4*)&xmS[lt * 4 + j][c0];
#pragma unroll
      for (int oi = 0; oi < 4; ++oi) pr[oi] = *(const float4*)&projS[w * 16 + lo * 4 + oi][c0];
#pragma unroll
      for (int j = 0; j < 4; ++j)
#pragma unroll
        for (int oi = 0; oi < 4; ++oi) {
          float a = acc[j * 4 + oi];
          a = fmaf(xr[j].x, pr[oi].x, a);
          a = fmaf(xr[j].y, pr[oi].y, a);
          a = fmaf(xr[j].z, pr[oi].z, a);
          a = fmaf(xr[j].w, pr[oi].w, a);
          acc[j * 4 + oi] = a;
        }
    }
#pragma unroll
    for (int oi = 0; oi < 4; ++oi) {
      int o = obase + oi;
      float4 v = make_float4(acc[0 * 4 + oi], acc[1 * 4 + oi],
                             acc[2 * 4 + oi], acc[3 * 4 + oi]);
      *(float4*)&out[((size_t)(b * OUT_ + o)) * L_ + t0 + lt * 4] = v;
    }
  }
}

extern "C" void kernel_launch(void* const* d_in, const int* in_sizes, int n_in,
                              void* d_out, int out_size, void* d_ws, size_t ws_size,
                              hipStream_t stream) {
  const float* x = (const float*)d_in[0];
  const float* norm_g = (const float*)d_in[1];
  const float* norm_b = (const float*)d_in[2];
  const float* proj_W = (const float*)d_in[3];
  const float* proj_b = (const float*)d_in[4];
  const float* skip = (const float*)d_in[5];
  const float* se_W1 = (const float*)d_in[6];
  const float* se_W2 = (const float*)d_in[7];
  const float* in_W = (const float*)d_in[8];
  const float* conv_W = (const float*)d_in[9];
  const float* conv_b = (const float*)d_in[10];
  const float* xproj_W = (const float*)d_in[11];
  const float* dt_W = (const float*)d_in[12];
  const float* dt_b = (const float*)d_in[13];
  const float* A_log = (const float*)d_in[14];
  const float* D_p = (const float*)d_in[15];
  const float* out_W = (const float*)d_in[16];
  float* out = (float*)d_out;

  // workspace (~101 MiB). YS2 aliases Qp (k3c writes it after k3b consumed Q).
  float* XN = (float*)d_ws;                         // B*L*C f32
  float* SUMYF = XN + (size_t)B_ * L_ * C_;         // NI*DI
  float* SUMXN = SUMYF + NI * DI;                   // B*C
  float* GATES = SUMXN + B_ * C_;                   // NI*DI
  float* Pp = GATES + NI * DI;                      // NI*NSEG*DI*DS f32
  float* Qp = Pp + (size_t)NI * NSEG * DI * DS;     // NI*NSEG*DI*DS f32
  float* BC2 = Qp + (size_t)NI * NSEG * DI * DS;    // NI*L*32 f32
  h16* YS2 = (h16*)Qp;                              // alias (same byte size)
  h16* SX2 = (h16*)(BC2 + (size_t)NI * L_ * 32);    // NI*L*DI h16
  h16* SDT2 = SX2 + (size_t)NI * L_ * DI;           // NI*L*DI h16

  hipMemsetAsync(SUMYF, 0, (size_t)(NI * DI + B_ * C_) * sizeof(float), stream);
  k2_prep<<<NI * 64, 256, 0, stream>>>(x, norm_g, norm_b, in_W, conv_W, conv_b,
                                       xproj_W, dt_W, dt_b, XN, SUMXN, SX2, SDT2,
                                       BC2);
  k3a_seg<<<NI * NSEG / 4, 256, 0, stream>>>(A_log, SDT2, SX2, BC2, Pp, Qp);
  k3b_comb<<<128, 256, 0, stream>>>(Pp, Qp);
  k3c_scan<<<NI * NSEG / 4, 256, 0, stream>>>(A_log, SDT2, SX2, BC2, XN, in_W, D_p,
                                              Pp, YS2, SUMYF);
  k4_gates<<<NI, 64, 0, stream>>>(out_W, se_W1, se_W2, skip, SUMYF, SUMXN, GATES);
  k5b_combine<<<NI * 64, 256, 0, stream>>>(out_W, skip, GATES, YS2, XN);
  k6_ln_proj<<<B_ * 64, 256, 0, stream>>>(norm_g, norm_b, proj_W, proj_b, XN, out);
}